// Round 2
// baseline (27.709 us; speedup 1.0000x reference)
//
#include <hip/hip_runtime.h>
#include <hip/hip_bf16.h>
#include <hip/hip_fp16.h>

#define NNODES 1024
#define FDIM   64
#define KOUT   32
#define NI     16          // i-rows per block

typedef _Float16 f16x8 __attribute__((ext_vector_type(8)));
typedef _Float16 f16x4 __attribute__((ext_vector_type(4)));
typedef float    f32x4 __attribute__((ext_vector_type(4)));

// Fused pairwise-MLP. Phase A: stage 80 emb rows (16 i, 64 j) to LDS as fp16,
// project with MFMA to left/right tiles. Phase B: per-wave staggered loop over
// the 16 i-rows, 4 MFMAs + in-register epilogue per (i, 16 j), full-wave
// batched stores every 4 iterations.
__global__ __launch_bounds__(256, 4) void fused_pair_mlp(
    const float* __restrict__ emb, const float* __restrict__ W1,
    const float* __restrict__ b1,
    const float* __restrict__ W2, const float* __restrict__ b2,
    const float* __restrict__ W3, const float* __restrict__ b3,
    float* __restrict__ out)
{
    const int tid  = threadIdx.x;
    const int wv   = tid >> 6;      // wave id 0..3
    const int ln   = tid & 63;
    const int ln16 = ln & 15;
    const int grp  = ln >> 4;       // k-group of 8

    const int b  = blockIdx.z;
    const int j0 = blockIdx.x * 64;      // 4 waves x 16 j
    const int i0 = blockIdx.y * NI;

    __shared__ _Float16 semb[80][72];       // 11.25 KiB staged emb rows (fp16)
    __shared__ _Float16 lleft[NI][FDIM];    // 2 KiB
    __shared__ _Float16 rtile[64][FDIM];    // 8 KiB

    // ---- phase A1: stage emb rows (rows 0..15 = i-tile, 16..79 = j-tile) ----
    {
        const float* ebase = emb + (size_t)b * NNODES * FDIM;
#pragma unroll
        for (int q = 0; q < 5; ++q) {
            const int idx  = q * 256 + tid;       // [0,1280) float4s
            const int row  = idx >> 4;            // [0,80)
            const int c4   = idx & 15;
            const int grow = (row < NI) ? (i0 + row) : (j0 + row - NI);
            const float4 v = *(const float4*)(ebase + (size_t)grow * FDIM + c4 * 4);
            f16x4 hv = { (_Float16)v.x, (_Float16)v.y, (_Float16)v.z, (_Float16)v.w };
            *(f16x4*)(&semb[row][c4 * 4]) = hv;
        }
    }

    // ---- W1 B-frags for this wave's output columns (global, L2-hot) ----
    const int ow = wv * 16 + ln16;        // output feature column of this lane
    f16x8 bW1L[2], bW1R[2];               // [k-half]
#pragma unroll
    for (int s = 0; s < 2; ++s)
#pragma unroll
        for (int e = 0; e < 8; ++e) {
            bW1L[s][e] = (_Float16)W1[(s * 32 + grp * 8 + e) * FDIM + ow];
            bW1R[s][e] = (_Float16)W1[(64 + s * 32 + grp * 8 + e) * FDIM + ow];
        }
    const float b1v = b1[ow];

    // ---- A-frags: W2^T, aW[k2tile t][khalf s] ----
    f16x8 aW[2][2];
#pragma unroll
    for (int t = 0; t < 2; ++t)
#pragma unroll
        for (int s = 0; s < 2; ++s)
#pragma unroll
            for (int e = 0; e < 8; ++e)
                aW[t][s][e] = (_Float16)W2[(s * 32 + grp * 8 + e) * KOUT
                                           + t * 16 + ln16];

    // ---- per-lane C-init (b2 folded) and W3 epilogue weights ----
    f32x4 c0i, c1i;
    float wa[8], wb[8];
#pragma unroll
    for (int r = 0; r < 4; ++r) {
        c0i[r] = b2[grp * 4 + r];
        c1i[r] = b2[16 + grp * 4 + r];
        const float w3lo = W3[grp * 4 + r];
        const float w3hi = W3[16 + grp * 4 + r];
        wa[r]     = 0.505f * w3lo;  wb[r]     = 0.495f * w3lo;
        wa[r + 4] = 0.505f * w3hi;  wb[r + 4] = 0.495f * w3hi;
    }
    const float bias3 = b3[0];

    __syncthreads();

    // ---- phase A2: left tile (1 m-tile of 16 i-rows) ----
    {
        const _Float16* ap = &semb[ln16][grp * 8];
        const f16x8 a0 = *(const f16x8*)ap;          // f = grp*8+e
        const f16x8 a1 = *(const f16x8*)(ap + 32);   // f = 32+grp*8+e
        f32x4 acc = {0.f, 0.f, 0.f, 0.f};
        acc = __builtin_amdgcn_mfma_f32_16x16x32_f16(a0, bW1L[0], acc, 0, 0, 0);
        acc = __builtin_amdgcn_mfma_f32_16x16x32_f16(a1, bW1L[1], acc, 0, 0, 0);
#pragma unroll
        for (int r = 0; r < 4; ++r)
            lleft[grp * 4 + r][ow] = (_Float16)(acc[r] + b1v);
    }
    // ---- phase A2: right tiles (4 m-tiles of 16 j-rows) ----
#pragma unroll
    for (int mt = 0; mt < 4; ++mt) {
        const _Float16* ap = &semb[NI + mt * 16 + ln16][grp * 8];
        const f16x8 a0 = *(const f16x8*)ap;
        const f16x8 a1 = *(const f16x8*)(ap + 32);
        f32x4 acc = {0.f, 0.f, 0.f, 0.f};
        acc = __builtin_amdgcn_mfma_f32_16x16x32_f16(a0, bW1R[0], acc, 0, 0, 0);
        acc = __builtin_amdgcn_mfma_f32_16x16x32_f16(a1, bW1R[1], acc, 0, 0, 0);
#pragma unroll
        for (int r = 0; r < 4; ++r)
            rtile[mt * 16 + grp * 4 + r][ow] = (_Float16)acc[r];
    }

    __syncthreads();

    // ---- this lane's right-row slice (j = j0 + wv*16 + ln16), from LDS ----
    const int jj = j0 + wv * 16 + ln16;
    const _Float16* rp = &rtile[wv * 16 + ln16][0];
    const f16x8 r0 = *(const f16x8*)(rp + grp * 8);
    const f16x8 r1 = *(const f16x8*)(rp + 32 + grp * 8);

    const _Float16 slope = (_Float16)0.01f;

    // one (i, 16 j) iteration: h = leaky(l+r), 4 MFMAs, epilogue reduce.
    // Waves start at staggered ii so the block's 4 waves hit different pipes.
#define PAIR_ITER(T, PACC) do {                                               \
    const int ii = ((T) + wv * 4) & (NI - 1);                                 \
    const _Float16* lrow = &lleft[ii][0];                                     \
    const f16x8 l0 = *(const f16x8*)(lrow + grp * 8);                         \
    const f16x8 l1 = *(const f16x8*)(lrow + 32 + grp * 8);                    \
    f16x8 h0 = l0 + r0;                                                       \
    f16x8 h1 = l1 + r1;                                                       \
    h0 = __builtin_elementwise_max(h0, h0 * slope);                           \
    h1 = __builtin_elementwise_max(h1, h1 * slope);                           \
    f32x4 acc0 = c0i;                                                         \
    f32x4 acc1 = c1i;                                                         \
    __builtin_amdgcn_s_setprio(1);                                            \
    acc0 = __builtin_amdgcn_mfma_f32_16x16x32_f16(aW[0][0], h0, acc0, 0,0,0); \
    acc0 = __builtin_amdgcn_mfma_f32_16x16x32_f16(aW[0][1], h1, acc0, 0,0,0); \
    acc1 = __builtin_amdgcn_mfma_f32_16x16x32_f16(aW[1][0], h0, acc1, 0,0,0); \
    acc1 = __builtin_amdgcn_mfma_f32_16x16x32_f16(aW[1][1], h1, acc1, 0,0,0); \
    __builtin_amdgcn_s_setprio(0);                                            \
    float pa = 0.f, pb = 0.f, pc = 0.f, pd = 0.f;                             \
    _Pragma("unroll")                                                         \
    for (int r = 0; r < 4; ++r) {                                             \
        pa = fmaf(wa[r],     acc0[r],        pa);                             \
        pb = fmaf(wb[r],     fabsf(acc0[r]), pb);                             \
        pc = fmaf(wa[r + 4], acc1[r],        pc);                             \
        pd = fmaf(wb[r + 4], fabsf(acc1[r]), pd);                             \
    }                                                                         \
    float p = (pa + pb) + (pc + pd);                                          \
    p += __shfl_xor(p, 16, 64);                                               \
    p += __shfl_xor(p, 32, 64);                                               \
    PACC = p + bias3;                                                         \
} while (0)

    for (int m = 0; m < 4; ++m) {
        float q0, q1, q2, q3;
        PAIR_ITER(m * 4 + 0, q0);
        PAIR_ITER(m * 4 + 1, q1);
        PAIR_ITER(m * 4 + 2, q2);
        PAIR_ITER(m * 4 + 3, q3);
        // lanes of group g store iteration (m*4+g)'s row -> one full-wave
        // 64-lane store covering 4 rows x 16 j.
        const int iibase = (m * 4 + wv * 4) & (NI - 1);   // multiple of 4
        float v = q0;
        v = (grp == 1) ? q1 : v;
        v = (grp == 2) ? q2 : v;
        v = (grp == 3) ? q3 : v;
        out[((size_t)b * NNODES + (i0 + iibase + grp)) * NNODES + jj] = v;
    }
#undef PAIR_ITER
}

extern "C" void kernel_launch(void* const* d_in, const int* in_sizes, int n_in,
                              void* d_out, int out_size, void* d_ws, size_t ws_size,
                              hipStream_t stream) {
    const float* emb = (const float*)d_in[0];
    const float* W1  = (const float*)d_in[1];
    const float* b1  = (const float*)d_in[2];
    const float* W2  = (const float*)d_in[3];
    const float* b2  = (const float*)d_in[4];
    const float* W3  = (const float*)d_in[5];
    const float* b3  = (const float*)d_in[6];
    float* out = (float*)d_out;
    (void)d_ws; (void)ws_size;

    fused_pair_mlp<<<dim3(NNODES / 64, NNODES / NI, 2), dim3(256), 0, stream>>>(
        emb, W1, b1, W2, b2, W3, b3, out);
}

// Round 4
// 26.480 us; speedup vs baseline: 1.0464x; 1.0464x over previous
//
#include <hip/hip_runtime.h>
#include <hip/hip_bf16.h>
#include <hip/hip_fp16.h>

#define NNODES 1024
#define FDIM   64
#define KOUT   32

typedef _Float16 f16x8 __attribute__((ext_vector_type(8)));
typedef _Float16 f16x4 __attribute__((ext_vector_type(4)));
typedef __fp16   fp16x2 __attribute__((ext_vector_type(2)));   // cvt_pkrtz result type
typedef float    f32x4  __attribute__((ext_vector_type(4)));
typedef float    f32x16 __attribute__((ext_vector_type(16)));

// Fused pairwise MLP, 32x32 tile per block.
// Phase A: stage 64 emb rows (32 i, 32 j) -> LDS fp16; project with verified
//   16x16x32 MFMAs to lleft (b1 folded) / rtile.
// Phase B: per wave: 8 i-rows x 32 j via mfma_f32_32x32x16_f16.
//   Layer-2: 4 chained MFMAs (K=64), A=W2^T in regs, B=leaky(l+r) packed fp16.
//   Layer-3: 2 MFMAs with A=W3 broadcast, B=cvt_pk(leaky(h2)) packed by the
//   verified C/D layout (row=(reg&3)+8*(reg>>2)+4*(lane>>5)) -> p(j) in all
//   D regs. No cross-lane ops anywhere in the main loop.
__global__ __launch_bounds__(256, 4) void fused_pair_mlp(
    const float* __restrict__ emb, const float* __restrict__ W1,
    const float* __restrict__ b1,
    const float* __restrict__ W2, const float* __restrict__ b2,
    const float* __restrict__ W3, const float* __restrict__ b3,
    float* __restrict__ out)
{
    const int tid  = threadIdx.x;
    const int wv   = tid >> 6;      // wave id 0..3
    const int ln   = tid & 63;
    const int ln16 = ln & 15;
    const int grp  = (ln >> 4) & 3; // 16-lane group within wave
    const int j32  = ln & 31;       // 32x32 operand row/col index
    const int hh   = ln >> 5;       // k-half for 32x32 operands

    const int b  = blockIdx.z;
    const int j0 = blockIdx.x * 32;
    const int i0 = blockIdx.y * 32;

    __shared__ _Float16 semb[64][72];    // 9 KiB staged emb rows (fp16, pad 72)
    __shared__ _Float16 lleft[32][64];   // 4 KiB   left tile (i rows)
    __shared__ _Float16 rtile[32][72];   // 4.5 KiB right tile (j rows, pad 72)

    // ---- phase A1: stage emb rows (0..31 = i-tile, 32..63 = j-tile) ----
    {
        const float* ebase = emb + (size_t)b * NNODES * FDIM;
#pragma unroll
        for (int q = 0; q < 4; ++q) {
            const int idx  = q * 256 + tid;       // [0,1024) float4s
            const int row  = idx >> 4;            // [0,64)
            const int c4   = idx & 15;
            const int grow = (row < 32) ? (i0 + row) : (j0 + row - 32);
            const float4 v = *(const float4*)(ebase + (size_t)grow * FDIM + c4 * 4);
            f16x4 hv = { (_Float16)v.x, (_Float16)v.y, (_Float16)v.z, (_Float16)v.w };
            *(f16x4*)(&semb[row][c4 * 4]) = hv;
        }
    }

    // ---- W1 B-frags for this wave's output columns (16x16x32, as verified) --
    const int ow = wv * 16 + ln16;        // output feature column of this lane
    f16x8 bW1L[2], bW1R[2];               // [k-half]
#pragma unroll
    for (int s = 0; s < 2; ++s)
#pragma unroll
        for (int e = 0; e < 8; ++e) {
            bW1L[s][e] = (_Float16)W1[(s * 32 + grp * 8 + e) * FDIM + ow];
            bW1R[s][e] = (_Float16)W1[(64 + s * 32 + grp * 8 + e) * FDIM + ow];
        }
    const float b1v = b1[ow];

    // ---- A-frags: W2^T for 32x32x16 (A row m=k2=j32, k=t*16+hh*8+e) ----
    f16x8 aW2[4];
#pragma unroll
    for (int t = 0; t < 4; ++t)
#pragma unroll
        for (int e = 0; e < 8; ++e)
            aW2[t][e] = (_Float16)W2[(t * 16 + hh * 8 + e) * KOUT + j32];

    // ---- A-frags: W3 broadcast, k-packing matched to 32x32 C/D layout ----
    // B slot (hh, e) of epilogue MFMA t holds acc reg r=t*8+e, whose k2 is
    // (e&3)+8*(e>>2)+16t+4hh; mirrored A slot must hold W3 at that k2.
    f16x8 a3[2];
#pragma unroll
    for (int t = 0; t < 2; ++t)
#pragma unroll
        for (int e = 0; e < 8; ++e)
            a3[t][e] = (_Float16)W3[(e & 3) + 8 * (e >> 2) + 16 * t + 4 * hh];

    // ---- layer-2 C-init: b2 by verified C/D row map ----
    f32x16 cinit;
#pragma unroll
    for (int r = 0; r < 16; ++r)
        cinit[r] = b2[(r & 3) + 8 * (r >> 2) + 4 * hh];
    // ---- layer-3 C-init: b3 broadcast ----
    f32x16 c3;
    const float bias3 = b3[0];
#pragma unroll
    for (int r = 0; r < 16; ++r)
        c3[r] = bias3;

    __syncthreads();

    // ---- phase A2: left tile (i rows 0..31), b1 folded ----
#pragma unroll
    for (int mt = 0; mt < 2; ++mt) {
        const _Float16* ap = &semb[mt * 16 + ln16][grp * 8];
        const f16x8 a0 = *(const f16x8*)ap;
        const f16x8 a1 = *(const f16x8*)(ap + 32);
        f32x4 acc = {0.f, 0.f, 0.f, 0.f};
        acc = __builtin_amdgcn_mfma_f32_16x16x32_f16(a0, bW1L[0], acc, 0, 0, 0);
        acc = __builtin_amdgcn_mfma_f32_16x16x32_f16(a1, bW1L[1], acc, 0, 0, 0);
#pragma unroll
        for (int r = 0; r < 4; ++r)
            lleft[mt * 16 + grp * 4 + r][ow] = (_Float16)(acc[r] + b1v);
    }
    // ---- phase A2: right tile (j rows 0..31) ----
#pragma unroll
    for (int mt = 0; mt < 2; ++mt) {
        const _Float16* ap = &semb[32 + mt * 16 + ln16][grp * 8];
        const f16x8 a0 = *(const f16x8*)ap;
        const f16x8 a1 = *(const f16x8*)(ap + 32);
        f32x4 acc = {0.f, 0.f, 0.f, 0.f};
        acc = __builtin_amdgcn_mfma_f32_16x16x32_f16(a0, bW1R[0], acc, 0, 0, 0);
        acc = __builtin_amdgcn_mfma_f32_16x16x32_f16(a1, bW1R[1], acc, 0, 0, 0);
#pragma unroll
        for (int r = 0; r < 4; ++r)
            rtile[mt * 16 + grp * 4 + r][ow] = (_Float16)acc[r];
    }

    __syncthreads();

    // ---- this lane's right-row slice: rtile[j32], k chunks t*16+hh*8 ----
    f16x8 rj[4];
#pragma unroll
    for (int t = 0; t < 4; ++t)
        rj[t] = *(const f16x8*)(&rtile[j32][t * 16 + hh * 8]);

    const _Float16 slope = (_Float16)0.01f;
    float pprev = 0.f;

    // ---- phase B: 8 i-rows per wave, 32 j per iteration ----
#pragma unroll 2
    for (int q = 0; q < 8; ++q) {
        const int ii = wv * 8 + q;
        const _Float16* lrow = &lleft[ii][0];

        f32x16 acc = cinit;
#pragma unroll
        for (int t = 0; t < 4; ++t) {
            const f16x8 l = *(const f16x8*)(lrow + t * 16 + hh * 8); // broadcast
            f16x8 x = l + rj[t];
            x = __builtin_elementwise_max(x, x * slope);             // leaky fp16
            acc = __builtin_amdgcn_mfma_f32_32x32x16_f16(aW2[t], x, acc, 0, 0, 0);
        }

        // epilogue: pack leaky(h2) to fp16 in C/D reg order, 2 MFMAs with W3
        f16x8 pb0, pb1;
#pragma unroll
        for (int e = 0; e < 4; ++e) {
            const fp16x2 t0 = __builtin_amdgcn_cvt_pkrtz(acc[2 * e], acc[2 * e + 1]);
            pb0[2 * e] = (_Float16)t0[0]; pb0[2 * e + 1] = (_Float16)t0[1];
            const fp16x2 t1 = __builtin_amdgcn_cvt_pkrtz(acc[8 + 2 * e], acc[9 + 2 * e]);
            pb1[2 * e] = (_Float16)t1[0]; pb1[2 * e + 1] = (_Float16)t1[1];
        }
        pb0 = __builtin_elementwise_max(pb0, pb0 * slope);
        pb1 = __builtin_elementwise_max(pb1, pb1 * slope);

        f32x16 d = c3;
        d = __builtin_amdgcn_mfma_f32_32x32x16_f16(a3[0], pb0, d, 0, 0, 0);
        d = __builtin_amdgcn_mfma_f32_32x32x16_f16(a3[1], pb1, d, 0, 0, 0);
        const float p = d[0];   // all rows/regs equal p(j32)

        if (q & 1) {
            // full-wave store: hh=0 lanes -> row q-1 (pprev), hh=1 -> row q (p)
            const float v   = hh ? p : pprev;
            const int   row = i0 + wv * 8 + (q - 1) + hh;
            out[((size_t)b * NNODES + row) * NNODES + j0 + j32] = v;
        } else {
            pprev = p;
        }
    }
}

extern "C" void kernel_launch(void* const* d_in, const int* in_sizes, int n_in,
                              void* d_out, int out_size, void* d_ws, size_t ws_size,
                              hipStream_t stream) {
    const float* emb = (const float*)d_in[0];
    const float* W1  = (const float*)d_in[1];
    const float* b1  = (const float*)d_in[2];
    const float* W2  = (const float*)d_in[3];
    const float* b2  = (const float*)d_in[4];
    const float* W3  = (const float*)d_in[5];
    const float* b3  = (const float*)d_in[6];
    float* out = (float*)d_out;
    (void)d_ws; (void)ws_size;

    fused_pair_mlp<<<dim3(NNODES / 32, NNODES / 32, 2), dim3(256), 0, stream>>>(
        emb, W1, b1, W2, b2, W3, b3, out);
}

// Round 5
// 24.614 us; speedup vs baseline: 1.1258x; 1.0758x over previous
//
#include <hip/hip_runtime.h>
#include <hip/hip_bf16.h>
#include <hip/hip_fp16.h>

#define NNODES 1024
#define FDIM   64
#define KOUT   32
#define NJ     128          // j-cols per block (4 waves x 32)
#define NI     32           // i-rows per block

typedef _Float16 f16x8 __attribute__((ext_vector_type(8)));
typedef _Float16 f16x4 __attribute__((ext_vector_type(4)));
typedef float    f32x4  __attribute__((ext_vector_type(4)));
typedef float    f32x16 __attribute__((ext_vector_type(16)));

// Fused pairwise MLP, 32i x 128j tile per block (512 blocks, all co-resident).
// Phase A: stage 160 emb rows -> LDS fp16; project with verified 16x16x32
//   MFMAs to lleft (b1 folded, 32 rows) / rtile (128 rows).
// Phase B: per wave: 32 i-rows x 32 j via mfma_f32_32x32x16_f16 (layer 2,
//   K=64, A=W2^T in regs, B=leaky(l+r) packed fp16). Layer 3 in fp32:
//   per-lane fma reduction over this lane's 16 k2 rows (leaky via
//   0.505x+0.495|x|, abs modifier is free) + one shfl_xor(32) for the
//   partner half. Full-wave batched store every 2 iterations.
__global__ __launch_bounds__(256) void fused_pair_mlp(
    const float* __restrict__ emb, const float* __restrict__ W1,
    const float* __restrict__ b1,
    const float* __restrict__ W2, const float* __restrict__ b2,
    const float* __restrict__ W3, const float* __restrict__ b3,
    float* __restrict__ out)
{
    const int tid  = threadIdx.x;
    const int wv   = tid >> 6;      // wave id 0..3
    const int ln   = tid & 63;
    const int ln16 = ln & 15;
    const int grp  = (ln >> 4) & 3; // 16-lane group within wave
    const int j32  = ln & 31;       // 32x32 operand col index
    const int hh   = ln >> 5;       // k-half for 32x32 operands

    const int b  = blockIdx.z;
    const int j0 = blockIdx.x * NJ;
    const int i0 = blockIdx.y * NI;

    __shared__ _Float16 semb[160][72];    // 22.5 KiB staged emb rows
    __shared__ _Float16 lleft[NI][64];    // 4 KiB    left tile (i rows)
    __shared__ _Float16 rtile[NJ][72];    // 18 KiB   right tile (j rows)

    // ---- phase A1: stage emb rows (0..31 = i-tile, 32..159 = j-tile) ----
    {
        const float* ebase = emb + (size_t)b * NNODES * FDIM;
#pragma unroll
        for (int q = 0; q < 10; ++q) {
            const int idx  = q * 256 + tid;       // [0,2560) float4s
            const int row  = idx >> 4;            // [0,160)
            const int c4   = idx & 15;
            const int grow = (row < NI) ? (i0 + row) : (j0 + row - NI);
            const float4 v = *(const float4*)(ebase + (size_t)grow * FDIM + c4 * 4);
            f16x4 hv = { (_Float16)v.x, (_Float16)v.y, (_Float16)v.z, (_Float16)v.w };
            *(f16x4*)(&semb[row][c4 * 4]) = hv;
        }
    }

    // ---- W1 B-frags for this wave's output columns (16x16x32, verified) ----
    const int ow = wv * 16 + ln16;        // output feature column of this lane
    f16x8 bW1L[2], bW1R[2];               // [k-half]
#pragma unroll
    for (int s = 0; s < 2; ++s)
#pragma unroll
        for (int e = 0; e < 8; ++e) {
            bW1L[s][e] = (_Float16)W1[(s * 32 + grp * 8 + e) * FDIM + ow];
            bW1R[s][e] = (_Float16)W1[(64 + s * 32 + grp * 8 + e) * FDIM + ow];
        }
    const float b1v = b1[ow];

    // ---- A-frags: W2^T for 32x32x16 (A row m=k2=j32, k=t*16+hh*8+e) ----
    f16x8 aW2[4];
#pragma unroll
    for (int t = 0; t < 4; ++t)
#pragma unroll
        for (int e = 0; e < 8; ++e)
            aW2[t][e] = (_Float16)W2[(t * 16 + hh * 8 + e) * KOUT + j32];

    // ---- layer-2 C-init (b2) and layer-3 weights by verified C/D row map:
    //      k2(r) = (r&3) + 8*(r>>2) + 4*hh ----
    f32x16 cinit;
    float  w3f[16];
#pragma unroll
    for (int r = 0; r < 16; ++r) {
        const int k2 = (r & 3) + 8 * (r >> 2) + 4 * hh;
        cinit[r] = b2[k2];
        w3f[r]   = W3[k2];
    }
    const float bias3 = b3[0];

    __syncthreads();

    // ---- phase A2: left tile (i rows 0..31), b1 folded ----
#pragma unroll
    for (int mt = 0; mt < 2; ++mt) {
        const _Float16* ap = &semb[mt * 16 + ln16][grp * 8];
        const f16x8 a0 = *(const f16x8*)ap;
        const f16x8 a1 = *(const f16x8*)(ap + 32);
        f32x4 acc = {0.f, 0.f, 0.f, 0.f};
        acc = __builtin_amdgcn_mfma_f32_16x16x32_f16(a0, bW1L[0], acc, 0, 0, 0);
        acc = __builtin_amdgcn_mfma_f32_16x16x32_f16(a1, bW1L[1], acc, 0, 0, 0);
#pragma unroll
        for (int r = 0; r < 4; ++r)
            lleft[mt * 16 + grp * 4 + r][ow] = (_Float16)(acc[r] + b1v);
    }
    // ---- phase A2: right tile (j rows 0..127) ----
#pragma unroll
    for (int mt = 0; mt < 8; ++mt) {
        const _Float16* ap = &semb[NI + mt * 16 + ln16][grp * 8];
        const f16x8 a0 = *(const f16x8*)ap;
        const f16x8 a1 = *(const f16x8*)(ap + 32);
        f32x4 acc = {0.f, 0.f, 0.f, 0.f};
        acc = __builtin_amdgcn_mfma_f32_16x16x32_f16(a0, bW1R[0], acc, 0, 0, 0);
        acc = __builtin_amdgcn_mfma_f32_16x16x32_f16(a1, bW1R[1], acc, 0, 0, 0);
#pragma unroll
        for (int r = 0; r < 4; ++r)
            rtile[mt * 16 + grp * 4 + r][ow] = (_Float16)acc[r];
    }

    __syncthreads();

    // ---- this wave's right-row slice: rtile[wv*32 + j32] ----
    f16x8 rj[4];
#pragma unroll
    for (int t = 0; t < 4; ++t)
        rj[t] = *(const f16x8*)(&rtile[wv * 32 + j32][t * 16 + hh * 8]);

    const _Float16 slope = (_Float16)0.01f;
    const int jj = j0 + wv * 32 + j32;
    float pprev = 0.f;

    // ---- phase B: 32 i-rows, 32 j per iteration per wave ----
#pragma unroll 2
    for (int ii = 0; ii < NI; ++ii) {
        const _Float16* lrow = &lleft[ii][0];

        f32x16 acc = cinit;
#pragma unroll
        for (int t = 0; t < 4; ++t) {
            const f16x8 l = *(const f16x8*)(lrow + t * 16 + hh * 8); // broadcast
            f16x8 x = l + rj[t];
            x = __builtin_elementwise_max(x, x * slope);             // leaky fp16
            acc = __builtin_amdgcn_mfma_f32_32x32x16_f16(aW2[t], x, acc, 0, 0, 0);
        }

        // layer 3 in fp32: p = sum_k2 leaky(h2[k2])*W3[k2]
        // leaky(x)*w = 0.505w*x + 0.495w*|x|; abs input modifier is free.
        float pa = 0.f, pb = 0.f;
#pragma unroll
        for (int r = 0; r < 16; ++r) {
            pa = fmaf(w3f[r], acc[r],        pa);
            pb = fmaf(w3f[r], fabsf(acc[r]), pb);
        }
        float p = fmaf(0.505f, pa, 0.495f * pb);
        p += __shfl_xor(p, 32, 64);     // partner k-half
        p += bias3;

        if (ii & 1) {
            // full-wave store: hh=0 lanes -> row ii-1 (pprev), hh=1 -> row ii
            const float v   = hh ? p : pprev;
            const int   row = i0 + (ii - 1) + hh;
            out[((size_t)b * NNODES + row) * NNODES + jj] = v;
        } else {
            pprev = p;
        }
    }
}

extern "C" void kernel_launch(void* const* d_in, const int* in_sizes, int n_in,
                              void* d_out, int out_size, void* d_ws, size_t ws_size,
                              hipStream_t stream) {
    const float* emb = (const float*)d_in[0];
    const float* W1  = (const float*)d_in[1];
    const float* b1  = (const float*)d_in[2];
    const float* W2  = (const float*)d_in[3];
    const float* b2  = (const float*)d_in[4];
    const float* W3  = (const float*)d_in[5];
    const float* b3  = (const float*)d_in[6];
    float* out = (float*)d_out;
    (void)d_ws; (void)ws_size;

    fused_pair_mlp<<<dim3(NNODES / NJ, NNODES / NI, 2), dim3(256), 0, stream>>>(
        emb, W1, b1, W2, b2, W3, b3, out);
}

// Round 6
// 22.638 us; speedup vs baseline: 1.2240x; 1.0873x over previous
//
#include <hip/hip_runtime.h>
#include <hip/hip_bf16.h>
#include <hip/hip_fp16.h>

#define NNODES 1024
#define FDIM   64
#define KOUT   32
#define NJ     128          // j-cols per block (4 column-waves x 32)
#define NI     32           // i-rows per block (2 row-halves x 16)

typedef _Float16 f16x8 __attribute__((ext_vector_type(8)));
typedef _Float16 f16x4 __attribute__((ext_vector_type(4)));
typedef float    f32x4  __attribute__((ext_vector_type(4)));
typedef float    f32x16 __attribute__((ext_vector_type(16)));

// Fused pairwise MLP, 32i x 128j tile per block, 512 threads (8 waves).
// Wave (rh, cw) = (wv>>2, wv&3): rh = i-row half (16 rows), cw = j-col tile.
// 512 blocks x 8 waves = 4096 waves = 4 waves/SIMD (vs 2 in the previous
// round) -> discriminates latency-bound (b) vs overhead-bound (a) theories.
// Phase A: stage 160 emb rows -> LDS fp16; project via verified 16x16x32
//   MFMAs (A2 m-tiles split across the 8 waves).
// Phase B: per wave 16 i-rows x 32 j via mfma_f32_32x32x16_f16 (layer 2,
//   K=64) + fp32 fma layer-3 epilogue + one shfl_xor(32).
__global__ __launch_bounds__(512, 4) void fused_pair_mlp(
    const float* __restrict__ emb, const float* __restrict__ W1,
    const float* __restrict__ b1,
    const float* __restrict__ W2, const float* __restrict__ b2,
    const float* __restrict__ W3, const float* __restrict__ b3,
    float* __restrict__ out)
{
    const int tid  = threadIdx.x;
    const int wv   = tid >> 6;      // wave id 0..7
    const int cw   = wv & 3;        // column-wave (j tile)
    const int rh   = wv >> 2;       // row half (i rows)
    const int ln   = tid & 63;
    const int ln16 = ln & 15;
    const int grp  = (ln >> 4) & 3; // 16-lane group within wave
    const int j32  = ln & 31;       // 32x32 operand col index
    const int hh   = ln >> 5;       // k-half for 32x32 operands

    const int b  = blockIdx.z;
    const int j0 = blockIdx.x * NJ;
    const int i0 = blockIdx.y * NI;

    __shared__ _Float16 semb[160][72];    // 22.5 KiB staged emb rows
    __shared__ _Float16 lleft[NI][64];    // 4 KiB    left tile (i rows)
    __shared__ _Float16 rtile[NJ][72];    // 18 KiB   right tile (j rows)

    // ---- phase A1: stage emb rows (0..31 = i-tile, 32..159 = j-tile) ----
    {
        const float* ebase = emb + (size_t)b * NNODES * FDIM;
#pragma unroll
        for (int q = 0; q < 5; ++q) {
            const int idx  = q * 512 + tid;       // [0,2560) float4s
            const int row  = idx >> 4;            // [0,160)
            const int c4   = idx & 15;
            const int grow = (row < NI) ? (i0 + row) : (j0 + row - NI);
            const float4 v = *(const float4*)(ebase + (size_t)grow * FDIM + c4 * 4);
            f16x4 hv = { (_Float16)v.x, (_Float16)v.y, (_Float16)v.z, (_Float16)v.w };
            *(f16x4*)(&semb[row][c4 * 4]) = hv;
        }
    }

    // ---- W1 B-frags for this wave's output columns (16x16x32, verified) ----
    const int ow = cw * 16 + ln16;        // output feature column of this lane
    f16x8 bW1L[2], bW1R[2];               // [k-half]
#pragma unroll
    for (int s = 0; s < 2; ++s)
#pragma unroll
        for (int e = 0; e < 8; ++e) {
            bW1L[s][e] = (_Float16)W1[(s * 32 + grp * 8 + e) * FDIM + ow];
            bW1R[s][e] = (_Float16)W1[(64 + s * 32 + grp * 8 + e) * FDIM + ow];
        }
    const float b1v = b1[ow];

    // ---- A-frags: W2^T for 32x32x16 (A row m=k2=j32, k=t*16+hh*8+e) ----
    f16x8 aW2[4];
#pragma unroll
    for (int t = 0; t < 4; ++t)
#pragma unroll
        for (int e = 0; e < 8; ++e)
            aW2[t][e] = (_Float16)W2[(t * 16 + hh * 8 + e) * KOUT + j32];

    // ---- layer-2 C-init (b2) and layer-3 weights by verified C/D row map:
    //      k2(r) = (r&3) + 8*(r>>2) + 4*hh ----
    f32x16 cinit;
    float  w3f[16];
#pragma unroll
    for (int r = 0; r < 16; ++r) {
        const int k2 = (r & 3) + 8 * (r >> 2) + 4 * hh;
        cinit[r] = b2[k2];
        w3f[r]   = W3[k2];
    }
    const float bias3 = b3[0];

    __syncthreads();

    // ---- phase A2: left tile (i rows), row-half rh does m-tile rh ----
    {
        const _Float16* ap = &semb[rh * 16 + ln16][grp * 8];
        const f16x8 a0 = *(const f16x8*)ap;
        const f16x8 a1 = *(const f16x8*)(ap + 32);
        f32x4 acc = {0.f, 0.f, 0.f, 0.f};
        acc = __builtin_amdgcn_mfma_f32_16x16x32_f16(a0, bW1L[0], acc, 0, 0, 0);
        acc = __builtin_amdgcn_mfma_f32_16x16x32_f16(a1, bW1L[1], acc, 0, 0, 0);
#pragma unroll
        for (int r = 0; r < 4; ++r)
            lleft[rh * 16 + grp * 4 + r][ow] = (_Float16)(acc[r] + b1v);
    }
    // ---- phase A2: right tile (j rows), row-half rh does m-tiles 4rh..4rh+3 -
#pragma unroll
    for (int m = 0; m < 4; ++m) {
        const int mt = rh * 4 + m;
        const _Float16* ap = &semb[NI + mt * 16 + ln16][grp * 8];
        const f16x8 a0 = *(const f16x8*)ap;
        const f16x8 a1 = *(const f16x8*)(ap + 32);
        f32x4 acc = {0.f, 0.f, 0.f, 0.f};
        acc = __builtin_amdgcn_mfma_f32_16x16x32_f16(a0, bW1R[0], acc, 0, 0, 0);
        acc = __builtin_amdgcn_mfma_f32_16x16x32_f16(a1, bW1R[1], acc, 0, 0, 0);
#pragma unroll
        for (int r = 0; r < 4; ++r)
            rtile[mt * 16 + grp * 4 + r][ow] = (_Float16)acc[r];
    }

    __syncthreads();

    // ---- this wave's right-row slice: rtile[cw*32 + j32] ----
    f16x8 rj[4];
#pragma unroll
    for (int t = 0; t < 4; ++t)
        rj[t] = *(const f16x8*)(&rtile[cw * 32 + j32][t * 16 + hh * 8]);

    const _Float16 slope = (_Float16)0.01f;
    const int jj = j0 + cw * 32 + j32;
    float pprev = 0.f;

    // ---- phase B: 16 i-rows (this row-half), 32 j per iteration per wave ----
#pragma unroll 2
    for (int q = 0; q < 16; ++q) {
        const int ii = rh * 16 + q;
        const _Float16* lrow = &lleft[ii][0];

        f32x16 acc = cinit;
#pragma unroll
        for (int t = 0; t < 4; ++t) {
            const f16x8 l = *(const f16x8*)(lrow + t * 16 + hh * 8); // broadcast
            f16x8 x = l + rj[t];
            x = __builtin_elementwise_max(x, x * slope);             // leaky fp16
            acc = __builtin_amdgcn_mfma_f32_32x32x16_f16(aW2[t], x, acc, 0, 0, 0);
        }

        // layer 3 in fp32: p = sum_k2 leaky(h2[k2])*W3[k2]
        // leaky(x)*w = 0.505w*x + 0.495w*|x|; abs input modifier is free.
        float pa = 0.f, pb = 0.f;
#pragma unroll
        for (int r = 0; r < 16; ++r) {
            pa = fmaf(w3f[r], acc[r],        pa);
            pb = fmaf(w3f[r], fabsf(acc[r]), pb);
        }
        float p = fmaf(0.505f, pa, 0.495f * pb);
        p += __shfl_xor(p, 32, 64);     // partner k-half
        p += bias3;

        if (q & 1) {
            // full-wave store: hh=0 lanes -> row ii-1 (pprev), hh=1 -> row ii
            const float v   = hh ? p : pprev;
            const int   row = i0 + rh * 16 + (q - 1) + hh;
            out[((size_t)b * NNODES + row) * NNODES + jj] = v;
        } else {
            pprev = p;
        }
    }
}

extern "C" void kernel_launch(void* const* d_in, const int* in_sizes, int n_in,
                              void* d_out, int out_size, void* d_ws, size_t ws_size,
                              hipStream_t stream) {
    const float* emb = (const float*)d_in[0];
    const float* W1  = (const float*)d_in[1];
    const float* b1  = (const float*)d_in[2];
    const float* W2  = (const float*)d_in[3];
    const float* b2  = (const float*)d_in[4];
    const float* W3  = (const float*)d_in[5];
    const float* b3  = (const float*)d_in[6];
    float* out = (float*)d_out;
    (void)d_ws; (void)ws_size;

    fused_pair_mlp<<<dim3(NNODES / NJ, NNODES / NI, 2), dim3(512), 0, stream>>>(
        emb, W1, b1, W2, b2, W3, b3, out);
}

// Round 7
// 22.545 us; speedup vs baseline: 1.2290x; 1.0041x over previous
//
#include <hip/hip_runtime.h>
#include <hip/hip_bf16.h>
#include <hip/hip_fp16.h>

#define NNODES 1024
#define FDIM   64
#define KOUT   32
#define NJ     128          // j-cols per block (2 column-waves x 64)
#define NI     32           // i-rows per block (4 row-quarters x 8)

typedef _Float16 f16x8 __attribute__((ext_vector_type(8)));
typedef _Float16 f16x4 __attribute__((ext_vector_type(4)));
typedef float    f32x4  __attribute__((ext_vector_type(4)));
typedef float    f32x16 __attribute__((ext_vector_type(16)));

// Fused pairwise MLP, 32i x 128j tile per block, 512 threads (8 waves).
// Phase A (wave map: colgrp wv&3, half wv>>2, unchanged from verified r6):
//   stage 160 emb rows -> LDS fp16, project via 16x16x32 MFMAs.
// Phase B (wave map: cw = wv&1 -> 64 j, rh = wv>>1 -> 8 i-rows):
//   per i-row: ONE l-row read (4x ds_read_b128 broadcast) feeds TWO 32-j
//   subtiles (rj cached in regs) -> halves LDS traffic per pair. First
//   layer-2 MFMA consumes cinit directly as C (no per-iter acc-init movs).
//   Layer 3: fp32 fma with free |x| modifier + one shfl_xor(32).
//   One full-wave 64-float contiguous store per i-row.
__global__ __launch_bounds__(512, 4) void fused_pair_mlp(
    const float* __restrict__ emb, const float* __restrict__ W1,
    const float* __restrict__ b1,
    const float* __restrict__ W2, const float* __restrict__ b2,
    const float* __restrict__ W3, const float* __restrict__ b3,
    float* __restrict__ out)
{
    const int tid  = threadIdx.x;
    const int wv   = tid >> 6;      // wave id 0..7
    const int ln   = tid & 63;
    const int ln16 = ln & 15;
    const int grp  = (ln >> 4) & 3; // 16-lane group within wave
    const int j32  = ln & 31;       // 32x32 operand col index
    const int hh   = ln >> 5;       // k-half for 32x32 operands

    const int b  = blockIdx.z;
    const int j0 = blockIdx.x * NJ;
    const int i0 = blockIdx.y * NI;

    __shared__ _Float16 semb[160][72];    // 22.5 KiB staged emb rows
    __shared__ _Float16 lleft[NI][64];    // 4 KiB    left tile (i rows)
    __shared__ _Float16 rtile[NJ][72];    // 18 KiB   right tile (j rows)

    // ---- phase A1: stage emb rows (0..31 = i-tile, 32..159 = j-tile) ----
    {
        const float* ebase = emb + (size_t)b * NNODES * FDIM;
#pragma unroll
        for (int q = 0; q < 5; ++q) {
            const int idx  = q * 512 + tid;       // [0,2560) float4s
            const int row  = idx >> 4;            // [0,160)
            const int c4   = idx & 15;
            const int grow = (row < NI) ? (i0 + row) : (j0 + row - NI);
            const float4 v = *(const float4*)(ebase + (size_t)grow * FDIM + c4 * 4);
            f16x4 hv = { (_Float16)v.x, (_Float16)v.y, (_Float16)v.z, (_Float16)v.w };
            *(f16x4*)(&semb[row][c4 * 4]) = hv;
        }
    }

    // ---- phase-A wave map (as verified in r6): 4 col-groups x 2 halves ----
    const int cwA = wv & 3;
    const int rhA = wv >> 2;

    // ---- W1 B-frags for this wave's output columns (16x16x32, verified) ----
    const int ow = cwA * 16 + ln16;       // output feature column of this lane
    f16x8 bW1L[2], bW1R[2];               // [k-half]
#pragma unroll
    for (int s = 0; s < 2; ++s)
#pragma unroll
        for (int e = 0; e < 8; ++e) {
            bW1L[s][e] = (_Float16)W1[(s * 32 + grp * 8 + e) * FDIM + ow];
            bW1R[s][e] = (_Float16)W1[(64 + s * 32 + grp * 8 + e) * FDIM + ow];
        }
    const float b1v = b1[ow];

    // ---- A-frags: W2^T for 32x32x16 (A row m=k2=j32, k=t*16+hh*8+e) ----
    f16x8 aW2[4];
#pragma unroll
    for (int t = 0; t < 4; ++t)
#pragma unroll
        for (int e = 0; e < 8; ++e)
            aW2[t][e] = (_Float16)W2[(t * 16 + hh * 8 + e) * KOUT + j32];

    // ---- layer-2 C-init (b2) and layer-3 weights by verified C/D row map:
    //      k2(r) = (r&3) + 8*(r>>2) + 4*hh ----
    f32x16 cinit;
    float  w3f[16];
#pragma unroll
    for (int r = 0; r < 16; ++r) {
        const int k2 = (r & 3) + 8 * (r >> 2) + 4 * hh;
        cinit[r] = b2[k2];
        w3f[r]   = W3[k2];
    }
    const float bias3 = b3[0];

    __syncthreads();

    // ---- phase A2: left tile (i rows), half rhA does m-tile rhA ----
    {
        const _Float16* ap = &semb[rhA * 16 + ln16][grp * 8];
        const f16x8 a0 = *(const f16x8*)ap;
        const f16x8 a1 = *(const f16x8*)(ap + 32);
        f32x4 acc = {0.f, 0.f, 0.f, 0.f};
        acc = __builtin_amdgcn_mfma_f32_16x16x32_f16(a0, bW1L[0], acc, 0, 0, 0);
        acc = __builtin_amdgcn_mfma_f32_16x16x32_f16(a1, bW1L[1], acc, 0, 0, 0);
#pragma unroll
        for (int r = 0; r < 4; ++r)
            lleft[rhA * 16 + grp * 4 + r][ow] = (_Float16)(acc[r] + b1v);
    }
    // ---- phase A2: right tile (j rows), half rhA does m-tiles 4rhA..4rhA+3 --
#pragma unroll
    for (int m = 0; m < 4; ++m) {
        const int mt = rhA * 4 + m;
        const _Float16* ap = &semb[NI + mt * 16 + ln16][grp * 8];
        const f16x8 a0 = *(const f16x8*)ap;
        const f16x8 a1 = *(const f16x8*)(ap + 32);
        f32x4 acc = {0.f, 0.f, 0.f, 0.f};
        acc = __builtin_amdgcn_mfma_f32_16x16x32_f16(a0, bW1R[0], acc, 0, 0, 0);
        acc = __builtin_amdgcn_mfma_f32_16x16x32_f16(a1, bW1R[1], acc, 0, 0, 0);
#pragma unroll
        for (int r = 0; r < 4; ++r)
            rtile[mt * 16 + grp * 4 + r][ow] = (_Float16)acc[r];
    }

    __syncthreads();

    // ---- phase-B wave map: cw = j 64-col tile, rh = i 8-row quarter ----
    const int cw = wv & 1;
    const int rh = wv >> 1;

    // ---- cache both 32-j subtiles' right slices in regs (32 VGPR) ----
    f16x8 rj[2][4];
#pragma unroll
    for (int sub = 0; sub < 2; ++sub)
#pragma unroll
        for (int t = 0; t < 4; ++t)
            rj[sub][t] = *(const f16x8*)(&rtile[cw * 64 + sub * 32 + j32]
                                               [t * 16 + hh * 8]);

    const _Float16 slope = (_Float16)0.01f;
    float* orow = out + (size_t)b * NNODES * NNODES + j0 + cw * 64 + ln;

    // ---- phase B: 8 i-rows, 64 j per i-row (2 subtiles share one l-read) ----
    for (int q = 0; q < 8; ++q) {
        const int ii = rh * 8 + q;
        const _Float16* lrow = &lleft[ii][0];
        f16x8 l[4];
#pragma unroll
        for (int t = 0; t < 4; ++t)
            l[t] = *(const f16x8*)(lrow + t * 16 + hh * 8);   // broadcast read

        float p[2];
#pragma unroll
        for (int sub = 0; sub < 2; ++sub) {
            // t = 0 consumes cinit directly as C (no acc-init copy)
            f16x8 x = l[0] + rj[sub][0];
            x = __builtin_elementwise_max(x, x * slope);
            f32x16 acc = __builtin_amdgcn_mfma_f32_32x32x16_f16(aW2[0], x,
                                                                cinit, 0, 0, 0);
#pragma unroll
            for (int t = 1; t < 4; ++t) {
                x = l[t] + rj[sub][t];
                x = __builtin_elementwise_max(x, x * slope);
                acc = __builtin_amdgcn_mfma_f32_32x32x16_f16(aW2[t], x,
                                                             acc, 0, 0, 0);
            }

            // layer 3 in fp32: p = sum_k2 leaky(h2[k2])*W3[k2]
            // leaky(x)*w = 0.505w*x + 0.495w*|x|; abs modifier is free.
            float pa = 0.f, pb = 0.f;
#pragma unroll
            for (int r = 0; r < 16; ++r) {
                pa = fmaf(w3f[r], acc[r],        pa);
                pb = fmaf(w3f[r], fabsf(acc[r]), pb);
            }
            float pp = fmaf(0.505f, pa, 0.495f * pb);
            pp += __shfl_xor(pp, 32, 64);   // partner k-half
            p[sub] = pp + bias3;
        }

        // full-wave contiguous store: lane ln covers j = cw*64 + ln
        orow[(size_t)(i0 + ii) * NNODES] = hh ? p[1] : p[0];
    }
}

extern "C" void kernel_launch(void* const* d_in, const int* in_sizes, int n_in,
                              void* d_out, int out_size, void* d_ws, size_t ws_size,
                              hipStream_t stream) {
    const float* emb = (const float*)d_in[0];
    const float* W1  = (const float*)d_in[1];
    const float* b1  = (const float*)d_in[2];
    const float* W2  = (const float*)d_in[3];
    const float* b2  = (const float*)d_in[4];
    const float* W3  = (const float*)d_in[5];
    const float* b3  = (const float*)d_in[6];
    float* out = (float*)d_out;
    (void)d_ws; (void)ws_size;

    fused_pair_mlp<<<dim3(NNODES / NJ, NNODES / NI, 2), dim3(512), 0, stream>>>(
        emb, W1, b1, W2, b2, W3, b3, out);
}